// Round 18
// baseline (299.393 us; speedup 1.0000x reference)
//
#include <hip/hip_runtime.h>
#include <math.h>

#define N    5000
#define E    4
#define H    64
#define PV   300
#define RD   64
#define NS_  8
#define SP_  6
#define NI   (RD + NS_ + SP_)   // 78
#define GH   (2 * H)            // 128
#define MSGW (2 * E * H)        // 512
#define CAP  128
#define NPB  8                  // nodes per k_gru block (4 per wave, 2-way K split)
#define MSG_BPS 256             // k_msg blocks per (dir,e) slice

#define PK_S0 ((MSGW / 4) * GH)   // 16384 float4s: packed Wih_rz
#define PK_S1 ((MSGW / 4) * H)    //  8192 float4s: packed Wih_c
#define PK_S2 ((H / 4) * GH)      //  2048 float4s: packed Whh_rz
#define PK_S3 ((H / 4) * H)       //  1024 float4s: packed Whh_c
#define PK_TOT (PK_S0 + PK_S1 + PK_S2 + PK_S3)   // 27648 = 108*256

#define PRE_PACK_B 108
#define PRE_ZERO_B 40             // 40*256 >= 10000 int4
#define PRE_INIT_B 313            // 313*16 >= 5000 nodes
#define PRE_GRID (PRE_PACK_B + PRE_ZERO_B + PRE_INIT_B)   // 461

__device__ __forceinline__ float wsum(float v) {
    v += __shfl_xor(v, 32, 64);
    v += __shfl_xor(v, 16, 64);
    v += __shfl_xor(v, 8, 64);
    v += __shfl_xor(v, 4, 64);
    v += __shfl_xor(v, 2, 64);
    v += __shfl_xor(v, 1, 64);
    return v;
}

// ---------------------------------------------------------------------------
// K_pre: fused {weight pack | cnt zero | node init + hs(h0)} via block ranges.
// ---------------------------------------------------------------------------
__global__ __launch_bounds__(256) void k_pre(
    const float* __restrict__ Wih_rz, const float* __restrict__ Wih_c,
    const float* __restrict__ Whh_rz, const float* __restrict__ Whh_c,
    float4* __restrict__ Prz, float4* __restrict__ Pc,
    float4* __restrict__ Phrz, float4* __restrict__ Phc,
    int4* __restrict__ cnts,
    const float* __restrict__ NV, const float* __restrict__ NSt,
    const float* __restrict__ SPos, const float* __restrict__ Wred,
    const float* __restrict__ bred, const float* __restrict__ Winit,
    const float* __restrict__ binit, float* __restrict__ h,
    const float* __restrict__ Wout, const float* __restrict__ bout,
    const float* __restrict__ Win, const float* __restrict__ bin,
    float* __restrict__ hs_out, float* __restrict__ hs_in)
{
    __shared__ float nv[16 * PV];    // 19.2 KB (init branch)
    __shared__ float ni[16 * NI];    //  5.0 KB
    __shared__ float hn[16][H];      //  4.0 KB
    const int b = blockIdx.x;
    const int tid = threadIdx.x;

    if (b < PRE_PACK_B) {
        const int i = b * 256 + tid;             // < PK_TOT
        if (i < PK_S0) {
            const int kq = i / GH, col = i - kq * GH;
            Prz[i] = make_float4(Wih_rz[(4 * kq + 0) * GH + col],
                                 Wih_rz[(4 * kq + 1) * GH + col],
                                 Wih_rz[(4 * kq + 2) * GH + col],
                                 Wih_rz[(4 * kq + 3) * GH + col]);
        } else if (i < PK_S0 + PK_S1) {
            const int t = i - PK_S0;
            const int kq = t / H, col = t - kq * H;
            Pc[t] = make_float4(Wih_c[(4 * kq + 0) * H + col],
                                Wih_c[(4 * kq + 1) * H + col],
                                Wih_c[(4 * kq + 2) * H + col],
                                Wih_c[(4 * kq + 3) * H + col]);
        } else if (i < PK_S0 + PK_S1 + PK_S2) {
            const int t = i - PK_S0 - PK_S1;
            const int kq = t / GH, col = t - kq * GH;
            Phrz[t] = make_float4(Whh_rz[(4 * kq + 0) * GH + col],
                                  Whh_rz[(4 * kq + 1) * GH + col],
                                  Whh_rz[(4 * kq + 2) * GH + col],
                                  Whh_rz[(4 * kq + 3) * GH + col]);
        } else {
            const int t = i - PK_S0 - PK_S1 - PK_S2;
            const int kq = t / H, col = t - kq * H;
            Phc[t] = make_float4(Whh_c[(4 * kq + 0) * H + col],
                                 Whh_c[(4 * kq + 1) * H + col],
                                 Whh_c[(4 * kq + 2) * H + col],
                                 Whh_c[(4 * kq + 3) * H + col]);
        }
    } else if (b < PRE_PACK_B + PRE_ZERO_B) {
        const int i = (b - PRE_PACK_B) * 256 + tid;
        if (i < (2 * E * N) / 4) cnts[i] = make_int4(0, 0, 0, 0);
    } else {
        // ---- node init + hs: 16 nodes per block (4 waves x 4 nodes) ----
        const int n0 = (b - PRE_PACK_B - PRE_ZERO_B) * 16;
        const int j = tid & 63;
        const int w = tid >> 6;
        const int nb = w * 4;

        for (int idx = tid; idx < 16 * PV; idx += 256) {
            const int n = n0 + idx / PV;
            nv[idx] = (n < N) ? NV[(size_t)n0 * PV + idx] : 0.f;
        }
        __syncthreads();

        float acc[4];
        {
            const float br = bred[j];
            #pragma unroll
            for (int nn = 0; nn < 4; ++nn) acc[nn] = br;
        }
        for (int k = 0; k < PV; ++k) {
            const float wg = Wred[k * RD + j];
            #pragma unroll
            for (int nn = 0; nn < 4; ++nn) acc[nn] += nv[(nb + nn) * PV + k] * wg;
        }
        #pragma unroll
        for (int nn = 0; nn < 4; ++nn) ni[(nb + nn) * NI + j] = tanhf(acc[nn]);
        if (j < NS_) {
            #pragma unroll
            for (int nn = 0; nn < 4; ++nn) {
                const int n = n0 + nb + nn;
                ni[(nb + nn) * NI + RD + j] = (n < N) ? NSt[(size_t)n * NS_ + j] : 0.f;
            }
        }
        if (j < SP_) {
            #pragma unroll
            for (int nn = 0; nn < 4; ++nn) {
                const int n = n0 + nb + nn;
                ni[(nb + nn) * NI + RD + NS_ + j] = (n < N) ? SPos[(size_t)n * SP_ + j] : 0.f;
            }
        }
        __syncthreads();

        float a2[4];
        {
            const float bi = binit[j];
            #pragma unroll
            for (int nn = 0; nn < 4; ++nn) a2[nn] = bi;
        }
        for (int k = 0; k < NI; ++k) {
            const float wg = Winit[k * H + j];
            #pragma unroll
            for (int nn = 0; nn < 4; ++nn) a2[nn] += ni[(nb + nn) * NI + k] * wg;
        }
        #pragma unroll
        for (int nn = 0; nn < 4; ++nn) {
            const int n = n0 + nb + nn;
            const float hv = tanhf(a2[nn]);
            hn[nb + nn][j] = hv;
            if (n < N) h[(size_t)n * H + j] = hv;
        }
        __syncthreads();

        // ---- hs for these 16 nodes: wave w handles e = w
        const int e = w;
        float aO[16], aI[16];
        {
            const float bO = bout[e * H + j], bI = bin[e * H + j];
            #pragma unroll
            for (int nn = 0; nn < 16; ++nn) { aO[nn] = bO; aI[nn] = bI; }
        }
        for (int k = 0; k < H; ++k) {
            const float wo = Wout[(e * H + k) * H + j];
            const float wi = Win[(e * H + k) * H + j];
            #pragma unroll
            for (int nn = 0; nn < 16; ++nn) {
                const float hv = hn[nn][k];
                aO[nn] += hv * wo;
                aI[nn] += hv * wi;
            }
        }
        #pragma unroll
        for (int nn = 0; nn < 16; ++nn) {
            const int n = n0 + nn;
            if (n < N) {
                hs_out[((size_t)e * N + n) * H + j] = tanhf(aO[nn]);
                hs_in[((size_t)e * N + n) * H + j]  = tanhf(aI[nn]);
            }
        }
    }
}

// ---------------------------------------------------------------------------
// K1 v3: build lists — wave-per-row, atomic-free scan.  4 rows per block
// (wave = row); ballot prefix keeps the write cursor in a scalar register.
// ---------------------------------------------------------------------------
__global__ __launch_bounds__(256) void k_build(
    const float* __restrict__ A, int* __restrict__ cnt_out, int* __restrict__ cnt_in,
    unsigned short* __restrict__ idx_out, unsigned short* __restrict__ idx_in)
{
    __shared__ unsigned short s_cols[4][CAP];
    __shared__ int s_cnt[4];
    const int w = threadIdx.x >> 6;
    const int lane = threadIdx.x & 63;
    const int r = blockIdx.x * 4 + w;          // e*N + n
    const int e = r / N;
    const int n = r - e * N;

    const float4* row = (const float4*)(A + (size_t)r * N);
    int base = 0;
    for (int it = 0; it < 20; ++it) {          // 20*64 = 1280 >= 1250
        const int c = it * 64 + lane;
        float4 v = make_float4(0.f, 0.f, 0.f, 0.f);
        if (c < N / 4) v = row[c];
        #pragma unroll
        for (int comp = 0; comp < 4; ++comp) {
            const float val = (comp == 0) ? v.x : (comp == 1) ? v.y : (comp == 2) ? v.z : v.w;
            const bool p = (val != 0.f);
            const unsigned long long m = __ballot(p);
            if (p) {
                const int pos = base + (int)__popcll(m & ((1ull << lane) - 1ull));
                if (pos < CAP) s_cols[w][pos] = (unsigned short)(4 * c + comp);
            }
            base += (int)__popcll(m);
        }
    }
    const int cnt = min(base, CAP);
    if (lane == 0) s_cnt[w] = cnt;
    __syncthreads();

    // write out-list + scatter in-list (per wave, own row)
    const int cw = s_cnt[w];
    for (int i = lane; i < cw; i += 64) {
        const unsigned short m = s_cols[w][i];
        idx_out[(size_t)r * CAP + i] = m;
        const int p = atomicAdd(&cnt_in[e * N + m], 1);
        if (p < CAP) idx_in[(size_t)(e * N + m) * CAP + p] = (unsigned short)n;
    }
    if (lane == 0) cnt_out[r] = cw;
}

// ---------------------------------------------------------------------------
// K3 v3: XCD-sliced sparse aggregation (slice = blockIdx & 7 -> one XCD).
// ---------------------------------------------------------------------------
__global__ __launch_bounds__(256) void k_msg(
    const float* __restrict__ hs_out, const float* __restrict__ hs_in,
    const int* __restrict__ cnt_out, const int* __restrict__ cnt_in,
    const unsigned short* __restrict__ idx_out, const unsigned short* __restrict__ idx_in,
    float* __restrict__ msg)
{
    const int slice = blockIdx.x & 7;    // -> one XCD per slice (round-robin)
    const int sb = blockIdx.x >> 3;      // block index within slice
    const int dir = slice >> 2;
    const int e = slice & 3;
    const int tid = threadIdx.x;
    const int wv = tid >> 6;             // 0..3
    const int lane = tid & 63;
    const int g = lane >> 4;             // row-group 0..3
    const int l = lane & 15;             // float4 column within row

    const float4* hs4 = (const float4*)((dir ? hs_in : hs_out) + (size_t)e * N * H);
    const int* cnt = (dir ? cnt_in : cnt_out) + e * N;
    const unsigned short* idx = (dir ? idx_in : idx_out) + (size_t)e * N * CAP;
    float4* mdst = (float4*)msg;

    for (int n = sb * 4 + wv; n < N; n += MSG_BPS * 4) {
        const int c = min(cnt[n], CAP);
        const unsigned short* lst = idx + (size_t)n * CAP;

        float ax = 0.f, ay = 0.f, az = 0.f, aw = 0.f;
        int i = g;
        for (; i + 12 < c; i += 16) {
            const int m0 = lst[i];
            const int m1 = lst[i + 4];
            const int m2 = lst[i + 8];
            const int m3 = lst[i + 12];
            const float4 v0 = hs4[(size_t)m0 * (H / 4) + l];
            const float4 v1 = hs4[(size_t)m1 * (H / 4) + l];
            const float4 v2 = hs4[(size_t)m2 * (H / 4) + l];
            const float4 v3 = hs4[(size_t)m3 * (H / 4) + l];
            ax += (v0.x + v1.x) + (v2.x + v3.x);
            ay += (v0.y + v1.y) + (v2.y + v3.y);
            az += (v0.z + v1.z) + (v2.z + v3.z);
            aw += (v0.w + v1.w) + (v2.w + v3.w);
        }
        for (; i < c; i += 4) {
            const float4 v = hs4[(size_t)lst[i] * (H / 4) + l];
            ax += v.x; ay += v.y; az += v.z; aw += v.w;
        }

        ax += __shfl_xor(ax, 16, 64); ay += __shfl_xor(ay, 16, 64);
        az += __shfl_xor(az, 16, 64); aw += __shfl_xor(aw, 16, 64);
        ax += __shfl_xor(ax, 32, 64); ay += __shfl_xor(ay, 32, 64);
        az += __shfl_xor(az, 32, 64); aw += __shfl_xor(aw, 32, 64);

        if (g == 0) {
            mdst[(size_t)n * (MSGW / 4) + dir * (E * H / 4) + e * (H / 4) + l] =
                make_float4(ax, ay, az, aw);
        }
    }
}

// ---------------------------------------------------------------------------
// K4 v9: fused GRU (+ optional hs epilogue for the NEXT iteration).
// ---------------------------------------------------------------------------
__global__ __launch_bounds__(256) void k_gru(
    const float* __restrict__ msg, const float* __restrict__ h,
    const float4* __restrict__ Prz, const float4* __restrict__ Pc,
    const float4* __restrict__ Phrz, const float4* __restrict__ Phc,
    const float* __restrict__ bih_rz, const float* __restrict__ bhh_rz,
    const float* __restrict__ bih_c, const float* __restrict__ bhh_c,
    const float* __restrict__ g_i2h, const float* __restrict__ be_i2h,
    const float* __restrict__ g_h2h, const float* __restrict__ be_h2h,
    const float* __restrict__ g_ci, const float* __restrict__ be_ci,
    const float* __restrict__ g_ch, const float* __restrict__ be_ch,
    float* __restrict__ h_out,
    const float* __restrict__ Wout, const float* __restrict__ bout,
    const float* __restrict__ Win, const float* __restrict__ bin,
    float* __restrict__ hs_out, float* __restrict__ hs_in,
    const int write_hs)
{
    __shared__ float pb[2][64][12];       // partials from kh=1 waves, 3 KB
    __shared__ float hn[NPB][H];          // new h for hs epilogue, 2 KB
    const int n0 = blockIdx.x * NPB;      // N % NPB == 0: no tail guards
    const int tid = threadIdx.x;
    const int j = tid & 63;
    const int wv = __builtin_amdgcn_readfirstlane(tid >> 6);  // wave-uniform SGPR
    const int kh = wv & 1;                // K half
    const int q  = wv >> 1;               // node quad 0/1
    const int nb = q * 4;

    const float4* ms4 = (const float4*)msg;
    const float4* hg4 = (const float4*)h;

    // ---- x parts over this wave's K half (packed weights)
    float a0[4], a1[4], c0[4];
    {
        const float v0 = kh ? 0.f : bih_rz[j];
        const float v1 = kh ? 0.f : bih_rz[H + j];
        const float vc = kh ? 0.f : bih_c[j];
        #pragma unroll
        for (int i = 0; i < 4; ++i) { a0[i] = v0; a1[i] = v1; c0[i] = vc; }
    }
    {
        const int kq0 = kh * (MSGW / 8);          // 0 or 64
        #pragma unroll 2
        for (int t = 0; t < MSGW / 8; ++t) {
            const int kq = kq0 + t;
            const float4 w0 = Prz[kq * GH + j];
            const float4 w1 = Prz[kq * GH + 64 + j];
            const float4 wc = Pc[kq * H + j];
            #pragma unroll
            for (int i = 0; i < 4; ++i) {
                const float4 m = ms4[(size_t)(n0 + nb + i) * (MSGW / 4) + kq];
                a0[i] += m.x * w0.x; a0[i] += m.y * w0.y;
                a0[i] += m.z * w0.z; a0[i] += m.w * w0.w;
                a1[i] += m.x * w1.x; a1[i] += m.y * w1.y;
                a1[i] += m.z * w1.z; a1[i] += m.w * w1.w;
                c0[i] += m.x * wc.x; c0[i] += m.y * wc.y;
                c0[i] += m.z * wc.z; c0[i] += m.w * wc.w;
            }
        }
    }

    // ---- h parts over this wave's K half (packed weights)
    float b0[4], b1[4], ch[4];
    {
        const float v0 = kh ? 0.f : bhh_rz[j];
        const float v1 = kh ? 0.f : bhh_rz[H + j];
        const float vc = kh ? 0.f : bhh_c[j];
        #pragma unroll
        for (int i = 0; i < 4; ++i) { b0[i] = v0; b1[i] = v1; ch[i] = vc; }
    }
    {
        const int kq0 = kh * (H / 8);             // 0 or 8
        #pragma unroll 2
        for (int t = 0; t < H / 8; ++t) {
            const int kq = kq0 + t;
            const float4 w0 = Phrz[kq * GH + j];
            const float4 w1 = Phrz[kq * GH + 64 + j];
            const float4 wc = Phc[kq * H + j];
            #pragma unroll
            for (int i = 0; i < 4; ++i) {
                const float4 m = hg4[(size_t)(n0 + nb + i) * (H / 4) + kq];
                b0[i] += m.x * w0.x; b0[i] += m.y * w0.y;
                b0[i] += m.z * w0.z; b0[i] += m.w * w0.w;
                b1[i] += m.x * w1.x; b1[i] += m.y * w1.y;
                b1[i] += m.z * w1.z; b1[i] += m.w * w1.w;
                ch[i] += m.x * wc.x; ch[i] += m.y * wc.y;
                ch[i] += m.z * wc.z; ch[i] += m.w * wc.w;
            }
        }
    }

    // ---- kh=1 waves publish x partials; kh=0 combines
    if (kh == 1) {
        #pragma unroll
        for (int i = 0; i < 4; ++i) {
            pb[q][j][i]     = a0[i];
            pb[q][j][4 + i] = a1[i];
            pb[q][j][8 + i] = c0[i];
        }
    }
    __syncthreads();
    if (kh == 0) {
        #pragma unroll
        for (int i = 0; i < 4; ++i) {
            a0[i] += pb[q][j][i];
            a1[i] += pb[q][j][4 + i];
            c0[i] += pb[q][j][8 + i];
        }
    }
    __syncthreads();
    if (kh == 1) {
        #pragma unroll
        for (int i = 0; i < 4; ++i) {
            pb[q][j][i]     = b0[i];
            pb[q][j][4 + i] = b1[i];
            pb[q][j][8 + i] = ch[i];
        }
    }
    __syncthreads();

    if (kh == 0) {
        #pragma unroll
        for (int i = 0; i < 4; ++i) {
            b0[i] += pb[q][j][i];
            b1[i] += pb[q][j][4 + i];
            ch[i] += pb[q][j][8 + i];
        }

        const float gi0 = g_i2h[j], gi1 = g_i2h[H + j], bi0 = be_i2h[j], bi1 = be_i2h[H + j];
        const float gh0 = g_h2h[j], gh1 = g_h2h[H + j], bh0 = be_h2h[j], bh1 = be_h2h[H + j];
        const float gci = g_ci[j], bci = be_ci[j], gchv = g_ch[j], bchv = be_ch[j];

        #pragma unroll
        for (int i = 0; i < 4; ++i) {
            float s  = wsum(a0[i] + a1[i]);
            float q_ = wsum(a0[i] * a0[i] + a1[i] * a1[i]);
            float mn = s * (1.f / GH);
            float vr = q_ * (1.f / GH) - mn * mn;
            float rs = rsqrtf(vr + 1e-5f);
            float x0 = (a0[i] - mn) * rs * gi0 + bi0;
            float x1 = (a1[i] - mn) * rs * gi1 + bi1;
            float s2  = wsum(b0[i] + b1[i]);
            float q2  = wsum(b0[i] * b0[i] + b1[i] * b1[i]);
            float mn2 = s2 * (1.f / GH);
            float vr2 = q2 * (1.f / GH) - mn2 * mn2;
            float rs2 = rsqrtf(vr2 + 1e-5f);
            float y0 = (b0[i] - mn2) * rs2 * gh0 + bh0;
            float y1 = (b1[i] - mn2) * rs2 * gh1 + bh1;
            const float r_ = 1.f / (1.f + expf(-(x0 + y0)));
            const float z_ = 1.f / (1.f + expf(-(x1 + y1)));

            float s3  = wsum(c0[i]);
            float q3  = wsum(c0[i] * c0[i]);
            float mn3 = s3 * (1.f / H);
            float vr3 = q3 * (1.f / H) - mn3 * mn3;
            float rs3 = rsqrtf(vr3 + 1e-5f);
            float xc = (c0[i] - mn3) * rs3 * gci + bci;
            float s4  = wsum(ch[i]);
            float q4  = wsum(ch[i] * ch[i]);
            float mn4 = s4 * (1.f / H);
            float vr4 = q4 * (1.f / H) - mn4 * mn4;
            float rs4 = rsqrtf(vr4 + 1e-5f);
            float hc = (ch[i] - mn4) * rs4 * gchv + bchv;
            float c  = tanhf(xc + r_ * hc);
            const int n = n0 + nb + i;
            const float hp = h[(size_t)n * H + j];
            const float hv = z_ * hp + (1.f - z_) * c;
            h_out[(size_t)n * H + j] = hv;
            hn[nb + i][j] = hv;
        }
    }
    __syncthreads();

    // ---- optional hs epilogue: wave wv handles e = wv for all 8 nodes
    if (write_hs) {
        const int e = wv;
        float aO[8], aI[8];
        {
            const float bO = bout[e * H + j], bI = bin[e * H + j];
            #pragma unroll
            for (int nn = 0; nn < 8; ++nn) { aO[nn] = bO; aI[nn] = bI; }
        }
        for (int k = 0; k < H; ++k) {
            const float wo = Wout[(e * H + k) * H + j];
            const float wi = Win[(e * H + k) * H + j];
            #pragma unroll
            for (int nn = 0; nn < 8; ++nn) {
                const float hv = hn[nn][k];
                aO[nn] += hv * wo;
                aI[nn] += hv * wi;
            }
        }
        #pragma unroll
        for (int nn = 0; nn < 8; ++nn) {
            hs_out[((size_t)e * N + n0 + nn) * H + j] = tanhf(aO[nn]);
            hs_in[((size_t)e * N + n0 + nn) * H + j]  = tanhf(aI[nn]);
        }
    }
}

// ---------------------------------------------------------------------------
extern "C" void kernel_launch(void* const* d_in, const int* in_sizes, int n_in,
                              void* d_out, int out_size, void* d_ws, size_t ws_size,
                              hipStream_t stream)
{
    const float* A      = (const float*)d_in[0];
    const float* nstate = (const float*)d_in[1];
    // d_in[2] node_ids unused
    const float* nvec   = (const float*)d_in[3];
    const float* nsp    = (const float*)d_in[4];
    const float* Wred   = (const float*)d_in[5];
    const float* bred   = (const float*)d_in[6];
    const float* Winit  = (const float*)d_in[7];
    const float* binit  = (const float*)d_in[8];
    const float* Wout   = (const float*)d_in[9];
    const float* bout   = (const float*)d_in[10];
    const float* Wine   = (const float*)d_in[11];
    const float* bine   = (const float*)d_in[12];
    const float* Wih_rz = (const float*)d_in[13];
    const float* bih_rz = (const float*)d_in[14];
    const float* Whh_rz = (const float*)d_in[15];
    const float* bhh_rz = (const float*)d_in[16];
    const float* Wih_c  = (const float*)d_in[17];
    const float* bih_c  = (const float*)d_in[18];
    const float* Whh_c  = (const float*)d_in[19];
    const float* bhh_c  = (const float*)d_in[20];
    const float* g_i2h  = (const float*)d_in[21];
    const float* be_i2h = (const float*)d_in[22];
    const float* g_h2h  = (const float*)d_in[23];
    const float* be_h2h = (const float*)d_in[24];
    const float* g_ci   = (const float*)d_in[25];
    const float* be_ci  = (const float*)d_in[26];
    const float* g_ch   = (const float*)d_in[27];
    const float* be_ch  = (const float*)d_in[28];

    char* ws = (char*)d_ws;
    size_t off = 0;
    auto alloc = [&](size_t bytes) {
        void* p = ws + off;
        off += (bytes + 255) & ~(size_t)255;
        return p;
    };
    float* h0  = (float*)alloc((size_t)N * H * 4);
    float* h1  = (float*)alloc((size_t)N * H * 4);
    float* hsO = (float*)alloc((size_t)E * N * H * 4);
    float* hsI = (float*)alloc((size_t)E * N * H * 4);
    float* msg = (float*)alloc((size_t)N * MSGW * 4);
    int* cnts  = (int*)alloc((size_t)2 * E * N * 4);
    int* cnt_out = cnts;
    int* cnt_in  = cnts + E * N;
    unsigned short* idxO = (unsigned short*)alloc((size_t)E * N * CAP * 2);
    unsigned short* idxI = (unsigned short*)alloc((size_t)E * N * CAP * 2);
    float4* Prz  = (float4*)alloc((size_t)PK_S0 * 16);
    float4* Pc   = (float4*)alloc((size_t)PK_S1 * 16);
    float4* Phrz = (float4*)alloc((size_t)PK_S2 * 16);
    float4* Phc  = (float4*)alloc((size_t)PK_S3 * 16);

    k_pre<<<PRE_GRID, 256, 0, stream>>>(Wih_rz, Wih_c, Whh_rz, Whh_c,
                                        Prz, Pc, Phrz, Phc, (int4*)cnts,
                                        nvec, nstate, nsp, Wred, bred, Winit, binit, h0,
                                        Wout, bout, Wine, bine, hsO, hsI);
    k_build<<<E * N / 4, 256, 0, stream>>>(A, cnt_out, cnt_in, idxO, idxI);

    // t = 0: gru writes h1 AND hs for the next iteration
    k_msg<<<8 * MSG_BPS, 256, 0, stream>>>(hsO, hsI, cnt_out, cnt_in, idxO, idxI, msg);
    k_gru<<<N / NPB, 256, 0, stream>>>(
        msg, h0, Prz, Pc, Phrz, Phc,
        bih_rz, bhh_rz, bih_c, bhh_c,
        g_i2h, be_i2h, g_h2h, be_h2h,
        g_ci, be_ci, g_ch, be_ch, h1,
        Wout, bout, Wine, bine, hsO, hsI, 1);

    // t = 1: final gru, no hs
    k_msg<<<8 * MSG_BPS, 256, 0, stream>>>(hsO, hsI, cnt_out, cnt_in, idxO, idxI, msg);
    k_gru<<<N / NPB, 256, 0, stream>>>(
        msg, h1, Prz, Pc, Phrz, Phc,
        bih_rz, bhh_rz, bih_c, bhh_c,
        g_i2h, be_i2h, g_h2h, be_h2h,
        g_ci, be_ci, g_ch, be_ch, (float*)d_out,
        Wout, bout, Wine, bine, hsO, hsI, 0);
}

// Round 19
// 271.616 us; speedup vs baseline: 1.1023x; 1.1023x over previous
//
#include <hip/hip_runtime.h>
#include <math.h>

#define N    5000
#define E    4
#define H    64
#define PV   300
#define RD   64
#define NS_  8
#define SP_  6
#define NI   (RD + NS_ + SP_)   // 78
#define GH   (2 * H)            // 128
#define MSGW (2 * E * H)        // 512
#define CAP  128
#define NPB  8                  // nodes per k_gru block (4 per wave, 2-way K split)
#define MSG_BPS 256             // k_msg blocks per (dir,e) slice

#define PK_S0 ((MSGW / 4) * GH)   // 16384 float4s: packed Wih_rz
#define PK_S1 ((MSGW / 4) * H)    //  8192 float4s: packed Wih_c
#define PK_S2 ((H / 4) * GH)      //  2048 float4s: packed Whh_rz
#define PK_S3 ((H / 4) * H)       //  1024 float4s: packed Whh_c
#define PK_TOT (PK_S0 + PK_S1 + PK_S2 + PK_S3)   // 27648 = 108*256

#define PRE_PACK_B 108
#define PRE_ZERO_B 40             // 40*256 >= 10000 int4
#define PRE_INIT_B 313            // 313*16 >= 5000 nodes
#define PRE_GRID (PRE_PACK_B + PRE_ZERO_B + PRE_INIT_B)   // 461

__device__ __forceinline__ float wsum(float v) {
    v += __shfl_xor(v, 32, 64);
    v += __shfl_xor(v, 16, 64);
    v += __shfl_xor(v, 8, 64);
    v += __shfl_xor(v, 4, 64);
    v += __shfl_xor(v, 2, 64);
    v += __shfl_xor(v, 1, 64);
    return v;
}

// ---------------------------------------------------------------------------
// K_pre: fused {weight pack | cnt zero | node init + hs(h0)} via block ranges.
// ---------------------------------------------------------------------------
__global__ __launch_bounds__(256) void k_pre(
    const float* __restrict__ Wih_rz, const float* __restrict__ Wih_c,
    const float* __restrict__ Whh_rz, const float* __restrict__ Whh_c,
    float4* __restrict__ Prz, float4* __restrict__ Pc,
    float4* __restrict__ Phrz, float4* __restrict__ Phc,
    int4* __restrict__ cnts,
    const float* __restrict__ NV, const float* __restrict__ NSt,
    const float* __restrict__ SPos, const float* __restrict__ Wred,
    const float* __restrict__ bred, const float* __restrict__ Winit,
    const float* __restrict__ binit, float* __restrict__ h,
    const float* __restrict__ Wout, const float* __restrict__ bout,
    const float* __restrict__ Win, const float* __restrict__ bin,
    float* __restrict__ hs_out, float* __restrict__ hs_in)
{
    __shared__ float nv[16 * PV];    // 19.2 KB (init branch)
    __shared__ float ni[16 * NI];    //  5.0 KB
    __shared__ float hn[16][H];      //  4.0 KB
    const int b = blockIdx.x;
    const int tid = threadIdx.x;

    if (b < PRE_PACK_B) {
        const int i = b * 256 + tid;             // < PK_TOT
        if (i < PK_S0) {
            const int kq = i / GH, col = i - kq * GH;
            Prz[i] = make_float4(Wih_rz[(4 * kq + 0) * GH + col],
                                 Wih_rz[(4 * kq + 1) * GH + col],
                                 Wih_rz[(4 * kq + 2) * GH + col],
                                 Wih_rz[(4 * kq + 3) * GH + col]);
        } else if (i < PK_S0 + PK_S1) {
            const int t = i - PK_S0;
            const int kq = t / H, col = t - kq * H;
            Pc[t] = make_float4(Wih_c[(4 * kq + 0) * H + col],
                                Wih_c[(4 * kq + 1) * H + col],
                                Wih_c[(4 * kq + 2) * H + col],
                                Wih_c[(4 * kq + 3) * H + col]);
        } else if (i < PK_S0 + PK_S1 + PK_S2) {
            const int t = i - PK_S0 - PK_S1;
            const int kq = t / GH, col = t - kq * GH;
            Phrz[t] = make_float4(Whh_rz[(4 * kq + 0) * GH + col],
                                  Whh_rz[(4 * kq + 1) * GH + col],
                                  Whh_rz[(4 * kq + 2) * GH + col],
                                  Whh_rz[(4 * kq + 3) * GH + col]);
        } else {
            const int t = i - PK_S0 - PK_S1 - PK_S2;
            const int kq = t / H, col = t - kq * H;
            Phc[t] = make_float4(Whh_c[(4 * kq + 0) * H + col],
                                 Whh_c[(4 * kq + 1) * H + col],
                                 Whh_c[(4 * kq + 2) * H + col],
                                 Whh_c[(4 * kq + 3) * H + col]);
        }
    } else if (b < PRE_PACK_B + PRE_ZERO_B) {
        const int i = (b - PRE_PACK_B) * 256 + tid;
        if (i < (2 * E * N) / 4) cnts[i] = make_int4(0, 0, 0, 0);
    } else {
        // ---- node init + hs: 16 nodes per block (4 waves x 4 nodes) ----
        const int n0 = (b - PRE_PACK_B - PRE_ZERO_B) * 16;
        const int j = tid & 63;
        const int w = tid >> 6;
        const int nb = w * 4;

        for (int idx = tid; idx < 16 * PV; idx += 256) {
            const int n = n0 + idx / PV;
            nv[idx] = (n < N) ? NV[(size_t)n0 * PV + idx] : 0.f;
        }
        __syncthreads();

        float acc[4];
        {
            const float br = bred[j];
            #pragma unroll
            for (int nn = 0; nn < 4; ++nn) acc[nn] = br;
        }
        for (int k = 0; k < PV; ++k) {
            const float wg = Wred[k * RD + j];
            #pragma unroll
            for (int nn = 0; nn < 4; ++nn) acc[nn] += nv[(nb + nn) * PV + k] * wg;
        }
        #pragma unroll
        for (int nn = 0; nn < 4; ++nn) ni[(nb + nn) * NI + j] = tanhf(acc[nn]);
        if (j < NS_) {
            #pragma unroll
            for (int nn = 0; nn < 4; ++nn) {
                const int n = n0 + nb + nn;
                ni[(nb + nn) * NI + RD + j] = (n < N) ? NSt[(size_t)n * NS_ + j] : 0.f;
            }
        }
        if (j < SP_) {
            #pragma unroll
            for (int nn = 0; nn < 4; ++nn) {
                const int n = n0 + nb + nn;
                ni[(nb + nn) * NI + RD + NS_ + j] = (n < N) ? SPos[(size_t)n * SP_ + j] : 0.f;
            }
        }
        __syncthreads();

        float a2[4];
        {
            const float bi = binit[j];
            #pragma unroll
            for (int nn = 0; nn < 4; ++nn) a2[nn] = bi;
        }
        for (int k = 0; k < NI; ++k) {
            const float wg = Winit[k * H + j];
            #pragma unroll
            for (int nn = 0; nn < 4; ++nn) a2[nn] += ni[(nb + nn) * NI + k] * wg;
        }
        #pragma unroll
        for (int nn = 0; nn < 4; ++nn) {
            const int n = n0 + nb + nn;
            const float hv = tanhf(a2[nn]);
            hn[nb + nn][j] = hv;
            if (n < N) h[(size_t)n * H + j] = hv;
        }
        __syncthreads();

        // ---- hs for these 16 nodes: wave w handles e = w
        const int e = w;
        float aO[16], aI[16];
        {
            const float bO = bout[e * H + j], bI = bin[e * H + j];
            #pragma unroll
            for (int nn = 0; nn < 16; ++nn) { aO[nn] = bO; aI[nn] = bI; }
        }
        for (int k = 0; k < H; ++k) {
            const float wo = Wout[(e * H + k) * H + j];
            const float wi = Win[(e * H + k) * H + j];
            #pragma unroll
            for (int nn = 0; nn < 16; ++nn) {
                const float hv = hn[nn][k];
                aO[nn] += hv * wo;
                aI[nn] += hv * wi;
            }
        }
        #pragma unroll
        for (int nn = 0; nn < 16; ++nn) {
            const int n = n0 + nn;
            if (n < N) {
                hs_out[((size_t)e * N + n) * H + j] = tanhf(aO[nn]);
                hs_in[((size_t)e * N + n) * H + j]  = tanhf(aI[nn]);
            }
        }
    }
}

// ---------------------------------------------------------------------------
// K1 (R17 form): block-per-row wave-ballot compaction, 2 float4/thread.
// ---------------------------------------------------------------------------
__global__ __launch_bounds__(256) void k_build(
    const float* __restrict__ A, int* __restrict__ cnt_out, int* __restrict__ cnt_in,
    unsigned short* __restrict__ idx_out, unsigned short* __restrict__ idx_in)
{
    const int r = blockIdx.x;          // e*N + n
    const int e = r / N;
    const int n = r - e * N;
    __shared__ int s_cnt;
    __shared__ int s_cols[CAP];
    if (threadIdx.x == 0) s_cnt = 0;
    __syncthreads();

    const float4* row = (const float4*)(A + (size_t)r * N);
    const int lane = threadIdx.x & 63;
    #pragma unroll
    for (int it = 0; it < 3; ++it) {
        const int c0 = threadIdx.x + it * 512;
        const int c1 = c0 + 256;
        float4 v0 = make_float4(0.f, 0.f, 0.f, 0.f);
        float4 v1 = make_float4(0.f, 0.f, 0.f, 0.f);
        if (c0 < N / 4) v0 = row[c0];
        if (c1 < N / 4) v1 = row[c1];
        #pragma unroll
        for (int half = 0; half < 2; ++half) {
            const float4 v = half ? v1 : v0;
            const int c = half ? c1 : c0;
            #pragma unroll
            for (int comp = 0; comp < 4; ++comp) {
                const float val = (comp == 0) ? v.x : (comp == 1) ? v.y : (comp == 2) ? v.z : v.w;
                const bool p = (val != 0.f);
                const unsigned long long m = __ballot(p);
                if (m) {
                    int base = 0;
                    if (lane == 0) base = atomicAdd(&s_cnt, (int)__popcll(m));
                    base = __shfl(base, 0, 64);
                    if (p) {
                        const int pos = base + (int)__popcll(m & ((1ull << lane) - 1ull));
                        if (pos < CAP) s_cols[pos] = 4 * c + comp;
                    }
                }
            }
        }
    }
    __syncthreads();
    const int cnt = min(s_cnt, CAP);
    if (threadIdx.x == 0) cnt_out[r] = cnt;
    for (int i = threadIdx.x; i < cnt; i += 256)
        idx_out[(size_t)r * CAP + i] = (unsigned short)s_cols[i];
    for (int i = threadIdx.x; i < cnt; i += 256) {
        const int m = s_cols[i];
        const int p = atomicAdd(&cnt_in[e * N + m], 1);
        if (p < CAP) idx_in[(size_t)(e * N + m) * CAP + p] = (unsigned short)n;
    }
}

// ---------------------------------------------------------------------------
// K3 v3: XCD-sliced sparse aggregation (slice = blockIdx & 7 -> one XCD).
// ---------------------------------------------------------------------------
__global__ __launch_bounds__(256) void k_msg(
    const float* __restrict__ hs_out, const float* __restrict__ hs_in,
    const int* __restrict__ cnt_out, const int* __restrict__ cnt_in,
    const unsigned short* __restrict__ idx_out, const unsigned short* __restrict__ idx_in,
    float* __restrict__ msg)
{
    const int slice = blockIdx.x & 7;    // -> one XCD per slice (round-robin)
    const int sb = blockIdx.x >> 3;      // block index within slice
    const int dir = slice >> 2;
    const int e = slice & 3;
    const int tid = threadIdx.x;
    const int wv = tid >> 6;             // 0..3
    const int lane = tid & 63;
    const int g = lane >> 4;             // row-group 0..3
    const int l = lane & 15;             // float4 column within row

    const float4* hs4 = (const float4*)((dir ? hs_in : hs_out) + (size_t)e * N * H);
    const int* cnt = (dir ? cnt_in : cnt_out) + e * N;
    const unsigned short* idx = (dir ? idx_in : idx_out) + (size_t)e * N * CAP;
    float4* mdst = (float4*)msg;

    for (int n = sb * 4 + wv; n < N; n += MSG_BPS * 4) {
        const int c = min(cnt[n], CAP);
        const unsigned short* lst = idx + (size_t)n * CAP;

        float ax = 0.f, ay = 0.f, az = 0.f, aw = 0.f;
        int i = g;
        for (; i + 12 < c; i += 16) {
            const int m0 = lst[i];
            const int m1 = lst[i + 4];
            const int m2 = lst[i + 8];
            const int m3 = lst[i + 12];
            const float4 v0 = hs4[(size_t)m0 * (H / 4) + l];
            const float4 v1 = hs4[(size_t)m1 * (H / 4) + l];
            const float4 v2 = hs4[(size_t)m2 * (H / 4) + l];
            const float4 v3 = hs4[(size_t)m3 * (H / 4) + l];
            ax += (v0.x + v1.x) + (v2.x + v3.x);
            ay += (v0.y + v1.y) + (v2.y + v3.y);
            az += (v0.z + v1.z) + (v2.z + v3.z);
            aw += (v0.w + v1.w) + (v2.w + v3.w);
        }
        for (; i < c; i += 4) {
            const float4 v = hs4[(size_t)lst[i] * (H / 4) + l];
            ax += v.x; ay += v.y; az += v.z; aw += v.w;
        }

        ax += __shfl_xor(ax, 16, 64); ay += __shfl_xor(ay, 16, 64);
        az += __shfl_xor(az, 16, 64); aw += __shfl_xor(aw, 16, 64);
        ax += __shfl_xor(ax, 32, 64); ay += __shfl_xor(ay, 32, 64);
        az += __shfl_xor(az, 32, 64); aw += __shfl_xor(aw, 32, 64);

        if (g == 0) {
            mdst[(size_t)n * (MSGW / 4) + dir * (E * H / 4) + e * (H / 4) + l] =
                make_float4(ax, ay, az, aw);
        }
    }
}

// ---------------------------------------------------------------------------
// K4 v9: fused GRU (+ optional hs epilogue for the NEXT iteration).
// ---------------------------------------------------------------------------
__global__ __launch_bounds__(256) void k_gru(
    const float* __restrict__ msg, const float* __restrict__ h,
    const float4* __restrict__ Prz, const float4* __restrict__ Pc,
    const float4* __restrict__ Phrz, const float4* __restrict__ Phc,
    const float* __restrict__ bih_rz, const float* __restrict__ bhh_rz,
    const float* __restrict__ bih_c, const float* __restrict__ bhh_c,
    const float* __restrict__ g_i2h, const float* __restrict__ be_i2h,
    const float* __restrict__ g_h2h, const float* __restrict__ be_h2h,
    const float* __restrict__ g_ci, const float* __restrict__ be_ci,
    const float* __restrict__ g_ch, const float* __restrict__ be_ch,
    float* __restrict__ h_out,
    const float* __restrict__ Wout, const float* __restrict__ bout,
    const float* __restrict__ Win, const float* __restrict__ bin,
    float* __restrict__ hs_out, float* __restrict__ hs_in,
    const int write_hs)
{
    __shared__ float pb[2][64][12];       // partials from kh=1 waves, 3 KB
    __shared__ float hn[NPB][H];          // new h for hs epilogue, 2 KB
    const int n0 = blockIdx.x * NPB;      // N % NPB == 0: no tail guards
    const int tid = threadIdx.x;
    const int j = tid & 63;
    const int wv = __builtin_amdgcn_readfirstlane(tid >> 6);  // wave-uniform SGPR
    const int kh = wv & 1;                // K half
    const int q  = wv >> 1;               // node quad 0/1
    const int nb = q * 4;

    const float4* ms4 = (const float4*)msg;
    const float4* hg4 = (const float4*)h;

    // ---- x parts over this wave's K half (packed weights)
    float a0[4], a1[4], c0[4];
    {
        const float v0 = kh ? 0.f : bih_rz[j];
        const float v1 = kh ? 0.f : bih_rz[H + j];
        const float vc = kh ? 0.f : bih_c[j];
        #pragma unroll
        for (int i = 0; i < 4; ++i) { a0[i] = v0; a1[i] = v1; c0[i] = vc; }
    }
    {
        const int kq0 = kh * (MSGW / 8);          // 0 or 64
        #pragma unroll 2
        for (int t = 0; t < MSGW / 8; ++t) {
            const int kq = kq0 + t;
            const float4 w0 = Prz[kq * GH + j];
            const float4 w1 = Prz[kq * GH + 64 + j];
            const float4 wc = Pc[kq * H + j];
            #pragma unroll
            for (int i = 0; i < 4; ++i) {
                const float4 m = ms4[(size_t)(n0 + nb + i) * (MSGW / 4) + kq];
                a0[i] += m.x * w0.x; a0[i] += m.y * w0.y;
                a0[i] += m.z * w0.z; a0[i] += m.w * w0.w;
                a1[i] += m.x * w1.x; a1[i] += m.y * w1.y;
                a1[i] += m.z * w1.z; a1[i] += m.w * w1.w;
                c0[i] += m.x * wc.x; c0[i] += m.y * wc.y;
                c0[i] += m.z * wc.z; c0[i] += m.w * wc.w;
            }
        }
    }

    // ---- h parts over this wave's K half (packed weights)
    float b0[4], b1[4], ch[4];
    {
        const float v0 = kh ? 0.f : bhh_rz[j];
        const float v1 = kh ? 0.f : bhh_rz[H + j];
        const float vc = kh ? 0.f : bhh_c[j];
        #pragma unroll
        for (int i = 0; i < 4; ++i) { b0[i] = v0; b1[i] = v1; ch[i] = vc; }
    }
    {
        const int kq0 = kh * (H / 8);             // 0 or 8
        #pragma unroll 2
        for (int t = 0; t < H / 8; ++t) {
            const int kq = kq0 + t;
            const float4 w0 = Phrz[kq * GH + j];
            const float4 w1 = Phrz[kq * GH + 64 + j];
            const float4 wc = Phc[kq * H + j];
            #pragma unroll
            for (int i = 0; i < 4; ++i) {
                const float4 m = hg4[(size_t)(n0 + nb + i) * (H / 4) + kq];
                b0[i] += m.x * w0.x; b0[i] += m.y * w0.y;
                b0[i] += m.z * w0.z; b0[i] += m.w * w0.w;
                b1[i] += m.x * w1.x; b1[i] += m.y * w1.y;
                b1[i] += m.z * w1.z; b1[i] += m.w * w1.w;
                ch[i] += m.x * wc.x; ch[i] += m.y * wc.y;
                ch[i] += m.z * wc.z; ch[i] += m.w * wc.w;
            }
        }
    }

    // ---- kh=1 waves publish x partials; kh=0 combines
    if (kh == 1) {
        #pragma unroll
        for (int i = 0; i < 4; ++i) {
            pb[q][j][i]     = a0[i];
            pb[q][j][4 + i] = a1[i];
            pb[q][j][8 + i] = c0[i];
        }
    }
    __syncthreads();
    if (kh == 0) {
        #pragma unroll
        for (int i = 0; i < 4; ++i) {
            a0[i] += pb[q][j][i];
            a1[i] += pb[q][j][4 + i];
            c0[i] += pb[q][j][8 + i];
        }
    }
    __syncthreads();
    if (kh == 1) {
        #pragma unroll
        for (int i = 0; i < 4; ++i) {
            pb[q][j][i]     = b0[i];
            pb[q][j][4 + i] = b1[i];
            pb[q][j][8 + i] = ch[i];
        }
    }
    __syncthreads();

    if (kh == 0) {
        #pragma unroll
        for (int i = 0; i < 4; ++i) {
            b0[i] += pb[q][j][i];
            b1[i] += pb[q][j][4 + i];
            ch[i] += pb[q][j][8 + i];
        }

        const float gi0 = g_i2h[j], gi1 = g_i2h[H + j], bi0 = be_i2h[j], bi1 = be_i2h[H + j];
        const float gh0 = g_h2h[j], gh1 = g_h2h[H + j], bh0 = be_h2h[j], bh1 = be_h2h[H + j];
        const float gci = g_ci[j], bci = be_ci[j], gchv = g_ch[j], bchv = be_ch[j];

        #pragma unroll
        for (int i = 0; i < 4; ++i) {
            float s  = wsum(a0[i] + a1[i]);
            float q_ = wsum(a0[i] * a0[i] + a1[i] * a1[i]);
            float mn = s * (1.f / GH);
            float vr = q_ * (1.f / GH) - mn * mn;
            float rs = rsqrtf(vr + 1e-5f);
            float x0 = (a0[i] - mn) * rs * gi0 + bi0;
            float x1 = (a1[i] - mn) * rs * gi1 + bi1;
            float s2  = wsum(b0[i] + b1[i]);
            float q2  = wsum(b0[i] * b0[i] + b1[i] * b1[i]);
            float mn2 = s2 * (1.f / GH);
            float vr2 = q2 * (1.f / GH) - mn2 * mn2;
            float rs2 = rsqrtf(vr2 + 1e-5f);
            float y0 = (b0[i] - mn2) * rs2 * gh0 + bh0;
            float y1 = (b1[i] - mn2) * rs2 * gh1 + bh1;
            const float r_ = 1.f / (1.f + expf(-(x0 + y0)));
            const float z_ = 1.f / (1.f + expf(-(x1 + y1)));

            float s3  = wsum(c0[i]);
            float q3  = wsum(c0[i] * c0[i]);
            float mn3 = s3 * (1.f / H);
            float vr3 = q3 * (1.f / H) - mn3 * mn3;
            float rs3 = rsqrtf(vr3 + 1e-5f);
            float xc = (c0[i] - mn3) * rs3 * gci + bci;
            float s4  = wsum(ch[i]);
            float q4  = wsum(ch[i] * ch[i]);
            float mn4 = s4 * (1.f / H);
            float vr4 = q4 * (1.f / H) - mn4 * mn4;
            float rs4 = rsqrtf(vr4 + 1e-5f);
            float hc = (ch[i] - mn4) * rs4 * gchv + bchv;
            float c  = tanhf(xc + r_ * hc);
            const int n = n0 + nb + i;
            const float hp = h[(size_t)n * H + j];
            const float hv = z_ * hp + (1.f - z_) * c;
            h_out[(size_t)n * H + j] = hv;
            hn[nb + i][j] = hv;
        }
    }
    __syncthreads();

    // ---- optional hs epilogue: wave wv handles e = wv for all 8 nodes
    if (write_hs) {
        const int e = wv;
        float aO[8], aI[8];
        {
            const float bO = bout[e * H + j], bI = bin[e * H + j];
            #pragma unroll
            for (int nn = 0; nn < 8; ++nn) { aO[nn] = bO; aI[nn] = bI; }
        }
        for (int k = 0; k < H; ++k) {
            const float wo = Wout[(e * H + k) * H + j];
            const float wi = Win[(e * H + k) * H + j];
            #pragma unroll
            for (int nn = 0; nn < 8; ++nn) {
                const float hv = hn[nn][k];
                aO[nn] += hv * wo;
                aI[nn] += hv * wi;
            }
        }
        #pragma unroll
        for (int nn = 0; nn < 8; ++nn) {
            hs_out[((size_t)e * N + n0 + nn) * H + j] = tanhf(aO[nn]);
            hs_in[((size_t)e * N + n0 + nn) * H + j]  = tanhf(aI[nn]);
        }
    }
}

// ---------------------------------------------------------------------------
extern "C" void kernel_launch(void* const* d_in, const int* in_sizes, int n_in,
                              void* d_out, int out_size, void* d_ws, size_t ws_size,
                              hipStream_t stream)
{
    const float* A      = (const float*)d_in[0];
    const float* nstate = (const float*)d_in[1];
    // d_in[2] node_ids unused
    const float* nvec   = (const float*)d_in[3];
    const float* nsp    = (const float*)d_in[4];
    const float* Wred   = (const float*)d_in[5];
    const float* bred   = (const float*)d_in[6];
    const float* Winit  = (const float*)d_in[7];
    const float* binit  = (const float*)d_in[8];
    const float* Wout   = (const float*)d_in[9];
    const float* bout   = (const float*)d_in[10];
    const float* Wine   = (const float*)d_in[11];
    const float* bine   = (const float*)d_in[12];
    const float* Wih_rz = (const float*)d_in[13];
    const float* bih_rz = (const float*)d_in[14];
    const float* Whh_rz = (const float*)d_in[15];
    const float* bhh_rz = (const float*)d_in[16];
    const float* Wih_c  = (const float*)d_in[17];
    const float* bih_c  = (const float*)d_in[18];
    const float* Whh_c  = (const float*)d_in[19];
    const float* bhh_c  = (const float*)d_in[20];
    const float* g_i2h  = (const float*)d_in[21];
    const float* be_i2h = (const float*)d_in[22];
    const float* g_h2h  = (const float*)d_in[23];
    const float* be_h2h = (const float*)d_in[24];
    const float* g_ci   = (const float*)d_in[25];
    const float* be_ci  = (const float*)d_in[26];
    const float* g_ch   = (const float*)d_in[27];
    const float* be_ch  = (const float*)d_in[28];

    char* ws = (char*)d_ws;
    size_t off = 0;
    auto alloc = [&](size_t bytes) {
        void* p = ws + off;
        off += (bytes + 255) & ~(size_t)255;
        return p;
    };
    float* h0  = (float*)alloc((size_t)N * H * 4);
    float* h1  = (float*)alloc((size_t)N * H * 4);
    float* hsO = (float*)alloc((size_t)E * N * H * 4);
    float* hsI = (float*)alloc((size_t)E * N * H * 4);
    float* msg = (float*)alloc((size_t)N * MSGW * 4);
    int* cnts  = (int*)alloc((size_t)2 * E * N * 4);
    int* cnt_out = cnts;
    int* cnt_in  = cnts + E * N;
    unsigned short* idxO = (unsigned short*)alloc((size_t)E * N * CAP * 2);
    unsigned short* idxI = (unsigned short*)alloc((size_t)E * N * CAP * 2);
    float4* Prz  = (float4*)alloc((size_t)PK_S0 * 16);
    float4* Pc   = (float4*)alloc((size_t)PK_S1 * 16);
    float4* Phrz = (float4*)alloc((size_t)PK_S2 * 16);
    float4* Phc  = (float4*)alloc((size_t)PK_S3 * 16);

    k_pre<<<PRE_GRID, 256, 0, stream>>>(Wih_rz, Wih_c, Whh_rz, Whh_c,
                                        Prz, Pc, Phrz, Phc, (int4*)cnts,
                                        nvec, nstate, nsp, Wred, bred, Winit, binit, h0,
                                        Wout, bout, Wine, bine, hsO, hsI);
    k_build<<<E * N, 256, 0, stream>>>(A, cnt_out, cnt_in, idxO, idxI);

    // t = 0: gru writes h1 AND hs for the next iteration
    k_msg<<<8 * MSG_BPS, 256, 0, stream>>>(hsO, hsI, cnt_out, cnt_in, idxO, idxI, msg);
    k_gru<<<N / NPB, 256, 0, stream>>>(
        msg, h0, Prz, Pc, Phrz, Phc,
        bih_rz, bhh_rz, bih_c, bhh_c,
        g_i2h, be_i2h, g_h2h, be_h2h,
        g_ci, be_ci, g_ch, be_ch, h1,
        Wout, bout, Wine, bine, hsO, hsI, 1);

    // t = 1: final gru, no hs
    k_msg<<<8 * MSG_BPS, 256, 0, stream>>>(hsO, hsI, cnt_out, cnt_in, idxO, idxI, msg);
    k_gru<<<N / NPB, 256, 0, stream>>>(
        msg, h1, Prz, Pc, Phrz, Phc,
        bih_rz, bhh_rz, bih_c, bhh_c,
        g_i2h, be_i2h, g_h2h, be_h2h,
        g_ci, be_ci, g_ch, be_ch, (float*)d_out,
        Wout, bout, Wine, bine, hsO, hsI, 0);
}